// Round 1
// baseline (370.308 us; speedup 1.0000x reference)
//
#include <hip/hip_runtime.h>

// BackEdgeConv2d: out = x * !(5 <= boxsum7x7(x >= 128/255, reflect-pad) <= 19)
// x: [16, 3, 1024, 1024] fp32.  Pure streaming stencil, HBM-bound.
//
// Design: one wave per (image, 32-row band). Each lane owns 16 contiguous
// columns (lane*16 .. lane*16+15) -> wave covers the full 1024-wide row.
// Per row: load 4x float4, threshold -> 16-bit mask in a u32, get the 3
// neighbor bits each side via shuffles (bit-reversed reflection at lanes
// 0/63), compute 16 horizontal 7-sums via popc on a sliding 7-bit window,
// pack them 4-per-u32 (bytes), and maintain the vertical 7-row sliding sum
// in byte-packed u32s with a 7-deep register ring. No LDS, no barriers.

constexpr int H = 1024;
constexpr int W = 1024;
constexpr int BH = 32;           // rows per band (per wave)
constexpr int NBANDS = H / BH;   // 32
constexpr int STEPS = BH + 6;    // 38 stencil rows per band (3 halo each side)

__global__ __launch_bounds__(64)
void backedge_kernel(const float* __restrict__ x, float* __restrict__ out) {
    const int lane = threadIdx.x;            // 0..63
    const int band = blockIdx.x;             // 0..31
    const int n    = blockIdx.y;             // 0..47 (B*C)
    const int r0   = band * BH;
    const float* __restrict__ xi = x   + (size_t)n * (size_t)(H * W);
    float*       __restrict__ oi = out + (size_t)n * (size_t)(H * W);
    const int col0 = lane * 16;
    const float THR = 128.0f / 255.0f;

    // ring of last 7 rows' packed horizontal sums (4 u32 = 16 byte-lanes)
    unsigned int hring[7][4];
#pragma unroll
    for (int i = 0; i < 7; ++i)
#pragma unroll
        for (int q = 0; q < 4; ++q) hring[i][q] = 0u;
    unsigned int vs[4] = {0u, 0u, 0u, 0u};   // packed vertical sliding sums

    for (int s = 0; s < STEPS; ++s) {
        int g = r0 - 3 + s;
        g = (g < 0) ? -g : g;                 // reflect top
        g = (g >= H) ? (2 * H - 2 - g) : g;   // reflect bottom
        const float* rp = xi + (size_t)g * W + col0;
        const float4 a0 = *(const float4*)(rp + 0);
        const float4 a1 = *(const float4*)(rp + 4);
        const float4 a2 = *(const float4*)(rp + 8);
        const float4 a3 = *(const float4*)(rp + 12);

        // 16 threshold bits: bit j <-> column col0 + j
        unsigned int own =
              (unsigned)(a0.x >= THR)        | ((unsigned)(a0.y >= THR) << 1)
            | ((unsigned)(a0.z >= THR) << 2) | ((unsigned)(a0.w >= THR) << 3)
            | ((unsigned)(a1.x >= THR) << 4) | ((unsigned)(a1.y >= THR) << 5)
            | ((unsigned)(a1.z >= THR) << 6) | ((unsigned)(a1.w >= THR) << 7)
            | ((unsigned)(a2.x >= THR) << 8) | ((unsigned)(a2.y >= THR) << 9)
            | ((unsigned)(a2.z >= THR) << 10)| ((unsigned)(a2.w >= THR) << 11)
            | ((unsigned)(a3.x >= THR) << 12)| ((unsigned)(a3.y >= THR) << 13)
            | ((unsigned)(a3.z >= THR) << 14)| ((unsigned)(a3.w >= THR) << 15);

        unsigned int lft = __shfl_up(own, 1);
        unsigned int rgt = __shfl_down(own, 1);
        if (lane == 0) {
            // reflected cols -3,-2,-1 -> cols 3,2,1 at bits 13,14,15
            lft = (((own >> 3) & 1u) << 13) | (((own >> 2) & 1u) << 14)
                | (((own >> 1) & 1u) << 15);
        }
        if (lane == 63) {
            // reflected cols 1024,1025,1026 -> cols 1022,1021,1020 at bits 0,1,2
            rgt = ((own >> 14) & 1u) | (((own >> 13) & 1u) << 1)
                | (((own >> 12) & 1u) << 2);
        }
        // w: bit i <-> column col0 + i - 3  (22 bits used)
        const unsigned int w = (lft >> 13) | (own << 3) | ((rgt & 7u) << 19);

        unsigned int hp[4];
#pragma unroll
        for (int q = 0; q < 4; ++q) {
            unsigned int h0 = __popc((w >> (4 * q + 0)) & 0x7Fu);
            unsigned int h1 = __popc((w >> (4 * q + 1)) & 0x7Fu);
            unsigned int h2 = __popc((w >> (4 * q + 2)) & 0x7Fu);
            unsigned int h3 = __popc((w >> (4 * q + 3)) & 0x7Fu);
            hp[q] = h0 | (h1 << 8) | (h2 << 16) | (h3 << 24);
        }

        // vertical sliding sum: add newest, drop oldest (byte-packed; each
        // byte <= 49 so base-256 digits never carry/borrow in the net result)
#pragma unroll
        for (int q = 0; q < 4; ++q) vs[q] += hp[q] - hring[0][q];
#pragma unroll
        for (int i = 0; i < 6; ++i)
#pragma unroll
            for (int q = 0; q < 4; ++q) hring[i][q] = hring[i + 1][q];
#pragma unroll
        for (int q = 0; q < 4; ++q) hring[6][q] = hp[q];

        if (s >= 6) {
            const int orow = r0 + s - 6;     // output row (center of window)
            const float* xp = xi + (size_t)orow * W + col0;
            float*       op = oi + (size_t)orow * W + col0;
            const float4 b0 = *(const float4*)(xp + 0);
            const float4 b1 = *(const float4*)(xp + 4);
            const float4 b2 = *(const float4*)(xp + 8);
            const float4 b3 = *(const float4*)(xp + 12);
            float4 o0, o1, o2, o3;
            // masked (zeroed) iff 5 <= csum <= 19  <=>  (csum-5) <= 14 unsigned
            o0.x = ((((vs[0]      ) & 0xFFu) - 5u) <= 14u) ? 0.0f : b0.x;
            o0.y = ((((vs[0] >>  8) & 0xFFu) - 5u) <= 14u) ? 0.0f : b0.y;
            o0.z = ((((vs[0] >> 16) & 0xFFu) - 5u) <= 14u) ? 0.0f : b0.z;
            o0.w = ((((vs[0] >> 24)        ) - 5u) <= 14u) ? 0.0f : b0.w;
            o1.x = ((((vs[1]      ) & 0xFFu) - 5u) <= 14u) ? 0.0f : b1.x;
            o1.y = ((((vs[1] >>  8) & 0xFFu) - 5u) <= 14u) ? 0.0f : b1.y;
            o1.z = ((((vs[1] >> 16) & 0xFFu) - 5u) <= 14u) ? 0.0f : b1.z;
            o1.w = ((((vs[1] >> 24)        ) - 5u) <= 14u) ? 0.0f : b1.w;
            o2.x = ((((vs[2]      ) & 0xFFu) - 5u) <= 14u) ? 0.0f : b2.x;
            o2.y = ((((vs[2] >>  8) & 0xFFu) - 5u) <= 14u) ? 0.0f : b2.y;
            o2.z = ((((vs[2] >> 16) & 0xFFu) - 5u) <= 14u) ? 0.0f : b2.z;
            o2.w = ((((vs[2] >> 24)        ) - 5u) <= 14u) ? 0.0f : b2.w;
            o3.x = ((((vs[3]      ) & 0xFFu) - 5u) <= 14u) ? 0.0f : b3.x;
            o3.y = ((((vs[3] >>  8) & 0xFFu) - 5u) <= 14u) ? 0.0f : b3.y;
            o3.z = ((((vs[3] >> 16) & 0xFFu) - 5u) <= 14u) ? 0.0f : b3.z;
            o3.w = ((((vs[3] >> 24)        ) - 5u) <= 14u) ? 0.0f : b3.w;
            *(float4*)(op + 0)  = o0;
            *(float4*)(op + 4)  = o1;
            *(float4*)(op + 8)  = o2;
            *(float4*)(op + 12) = o3;
        }
    }
}

extern "C" void kernel_launch(void* const* d_in, const int* in_sizes, int n_in,
                              void* d_out, int out_size, void* d_ws, size_t ws_size,
                              hipStream_t stream) {
    const float* x = (const float*)d_in[0];
    float* out = (float*)d_out;
    (void)in_sizes; (void)n_in; (void)d_ws; (void)ws_size; (void)out_size;
    dim3 grid(NBANDS, 16 * 3);   // 32 bands x 48 (B*C) = 1536 single-wave blocks
    backedge_kernel<<<grid, dim3(64), 0, stream>>>(x, out);
}